// Round 12
// baseline (211.963 us; speedup 1.0000x reference)
//
#include <hip/hip_runtime.h>

namespace {
constexpr int   S_GRID   = 14;
constexpr int   CH       = 30;
constexpr float L_COORD  = 5.0f;
constexpr float L_NOOBJ  = 0.5f;
constexpr float BOX_EPS  = 1e-20f;
constexpr int   BLOCK    = 256;
constexpr int   CPT      = 2;        // cells per thread: 60 floats = 15 x 16B
constexpr int   NSLOT    = 256;
constexpr int   SLOT_STRIDE = 16;    // 64B-separated partial slots
}

typedef float f32x4 __attribute__((ext_vector_type(4)));

// Per-cell loss (compile-time indexing only; exact transcription of reference).
__device__ __forceinline__ float cell_loss(const float* __restrict__ pv,
                                           const float* __restrict__ tv)
{
    const float objf   = ((tv[4] + tv[9]) > 0.0f) ? 1.0f : 0.0f;
    const float noobjf = 1.0f - objf;

    const float d4 = pv[4] - tv[4];
    const float d9 = pv[9] - tv[9];
    const float no_obj = noobjf * (d4 * d4 + d9 * d9);

    float cls = 0.0f;
    #pragma unroll
    for (int j = 10; j < CH; ++j) {
        const float d = pv[j] - tv[j];
        cls += d * d;
    }
    cls *= objf;

    float iou[2];
    constexpr float invS = 1.0f / (float)S_GRID;
    #pragma unroll
    for (int b = 0; b < 2; ++b) {
        const float* bp = pv + 5 * b;
        const float* bt = tv + 5 * b;
        const float txc = bt[0] * invS, tyc = bt[1] * invS;
        const float tx1 = txc - 0.5f * bt[2], tx2 = txc + 0.5f * bt[2];
        const float ty1 = tyc - 0.5f * bt[3], ty2 = tyc + 0.5f * bt[3];
        const float pxc = bp[0] * invS, pyc = bp[1] * invS;
        const float px1 = pxc - 0.5f * bp[2], px2 = pxc + 0.5f * bp[2];
        const float py1 = pyc - 0.5f * bp[3], py2 = pyc + 0.5f * bp[3];
        const float iw = fmaxf(fminf(tx2, px2) - fmaxf(tx1, px1), 0.0f);
        const float ih = fmaxf(fminf(ty2, py2) - fmaxf(ty1, py1), 0.0f);
        const float inter  = iw * ih;
        const float area_t = (tx2 - tx1) * (ty2 - ty1);
        const float area_p = (px2 - px1) * (py2 - py1);
        iou[b] = inter / (area_t + area_p - inter);
    }

    // a0 = iou0 > iou1 ; a1 = float(a0) <= iou1
    const bool  a0   = iou[0] > iou[1];
    const bool  a1   = (a0 ? 1.0f : 0.0f) <= iou[1];
    const float sel0 = a0 ? 1.0f : 0.0f;
    const float sel1 = a1 ? 1.0f : 0.0f;

    float contain = 0.0f, regr = 0.0f;
    #pragma unroll
    for (int b = 0; b < 2; ++b) {
        const float w  = objf * (b == 0 ? sel0 : sel1);
        const float* bp = pv + 5 * b;
        const float* bt = tv + 5 * b;
        const float dc = bp[4] - iou[b];
        contain += w * dc * dc;
        const float dx  = bp[0] - bt[0];
        const float dy  = bp[1] - bt[1];
        const float dsw = sqrtf(bp[2] + BOX_EPS) - sqrtf(bt[2] + BOX_EPS);
        const float dsh = sqrtf(bp[3] + BOX_EPS) - sqrtf(bt[3] + BOX_EPS);
        regr += w * (dx * dx + dy * dy + dsw * dsw + dsh * dsh);
    }

    return L_COORD * regr + contain + L_NOOBJ * no_obj + cls;
}

// Max bytes-in-flight streaming: 2 cells/thread, 15 dwordx4 loads per tensor
// issued back-to-back (30 KB in flight per wave — R6 demonstrated 2.65 TB/s
// HBM with this load shape), no LDS staging, no loop, no in-loop barriers.
// The asm "+v" pins defeat the rematerialization that inflated R6's traffic
// to 272 MB (VGPR_Count=36): values are forced register-resident, so each
// line is requested once while all 30 loads are concurrently outstanding
// (MSHR-merged). launch_bounds(256,1) frees the VGPR budget.
__global__ __launch_bounds__(BLOCK, 1) void yolo_main_kernel(
    const float* __restrict__ pred,
    const float* __restrict__ tgt,
    float* __restrict__ partial)
{
    __shared__ float wsum[BLOCK / 64];

    const int tid = threadIdx.x;
    const size_t pair = (size_t)blockIdx.x * BLOCK + tid;

    const f32x4* gp4 = reinterpret_cast<const f32x4*>(pred) + pair * 15;
    const f32x4* gt4 = reinterpret_cast<const f32x4*>(tgt) + pair * 15;

    f32x4 qp[15], qt[15];
    #pragma unroll
    for (int j = 0; j < 15; ++j) qp[j] = gp4[j];
    #pragma unroll
    for (int j = 0; j < 15; ++j) qt[j] = gt4[j];
    // pin staged vectors in registers: loads may not be re-issued after this
    #pragma unroll
    for (int j = 0; j < 15; ++j)
        asm volatile("" : "+v"(qp[j]), "+v"(qt[j]));

    float pv[CPT * CH], tv[CPT * CH];
    #pragma unroll
    for (int j = 0; j < 15; ++j) {
        #pragma unroll
        for (int k = 0; k < 4; ++k) {
            pv[4 * j + k] = qp[j][k];
            tv[4 * j + k] = qt[j][k];
        }
    }

    float acc = 0.0f;
    #pragma unroll
    for (int c = 0; c < CPT; ++c)
        acc += cell_loss(pv + c * CH, tv + c * CH);

    // ---- block reduction: per-wave shuffles, cross-wave via LDS
    #pragma unroll
    for (int off = 32; off > 0; off >>= 1)
        acc += __shfl_down(acc, off, 64);
    const int lane = tid & 63;
    const int wid  = tid >> 6;
    if (lane == 0) wsum[wid] = acc;
    __syncthreads();
    if (tid == 0) {
        const float s = (wsum[0] + wsum[1]) + (wsum[2] + wsum[3]);
        atomicAdd(&partial[(blockIdx.x & (NSLOT - 1)) * SLOT_STRIDE], s);
    }
}

// 256 partial slots -> single scalar output (plain store, no atomic)
__global__ __launch_bounds__(NSLOT) void yolo_finalize_kernel(
    const float* __restrict__ partial,
    float* __restrict__ out,
    float inv_n)
{
    __shared__ float wsum[NSLOT / 64];
    const int tid = threadIdx.x;
    float v = partial[tid * SLOT_STRIDE];
    #pragma unroll
    for (int off = 32; off > 0; off >>= 1)
        v += __shfl_down(v, off, 64);
    const int lane = tid & 63;
    const int wid  = tid >> 6;
    if (lane == 0) wsum[wid] = v;
    __syncthreads();
    if (tid == 0)
        out[0] = ((wsum[0] + wsum[1]) + (wsum[2] + wsum[3])) * inv_n;
}

extern "C" void kernel_launch(void* const* d_in, const int* in_sizes, int n_in,
                              void* d_out, int out_size, void* d_ws, size_t ws_size,
                              hipStream_t stream) {
    const float* pred = (const float*)d_in[0];
    const float* tgt  = (const float*)d_in[1];
    float* out     = (float*)d_out;
    float* partial = (float*)d_ws;    // NSLOT*SLOT_STRIDE floats = 16 KB

    const int ncells  = in_sizes[0] / CH;             // 4096*14*14 = 802816
    const int n_batch = ncells / (S_GRID * S_GRID);   // 4096
    const int grid    = ncells / (BLOCK * CPT);       // 1568 (exact)

    // d_ws is re-poisoned to 0xAA before every timed launch
    hipMemsetAsync(partial, 0, NSLOT * SLOT_STRIDE * sizeof(float), stream);
    yolo_main_kernel<<<grid, BLOCK, 0, stream>>>(pred, tgt, partial);
    yolo_finalize_kernel<<<1, NSLOT, 0, stream>>>(partial, out,
                                                  1.0f / (float)n_batch);
}